// Round 1
// baseline (250.313 us; speedup 1.0000x reference)
//
#include <hip/hip_runtime.h>
#include <hip/hip_bf16.h>
#include <cstdint>

#define B_TOT  2048
#define N_NODE 64
#define D_IN   256
#define D_OUT  256

typedef __attribute__((ext_vector_type(8))) short bf16x8;
typedef __attribute__((ext_vector_type(4))) float f32x4;

__device__ __forceinline__ unsigned short f2bf(float f) {
  union { float f; unsigned u; } v; v.f = f;
  unsigned r = v.u + 0x7FFFu + ((v.u >> 16) & 1u);   // round-to-nearest-even
  return (unsigned short)(r >> 16);
}

// Kernel A: h[b][n][o] = sum_i W[type[n]][o][i] * x[b][n][i]
// Workgroup: 64 batches x 256 outputs, one node. 4 waves in 2x2 layout.
// LDS k-layout is permuted so one MFMA fragment = one ds_read_b128; the same
// permutation is applied to A and B operands, so it cancels in the contraction.
__global__ __launch_bounds__(256)
void pernode_gemm(const float* __restrict__ x, const float* __restrict__ w,
                  const int* __restrict__ types, float* __restrict__ h)
{
  const int node = blockIdx.y;
  const int b0   = blockIdx.x * 64;
  const int t    = threadIdx.x;
  const int lane = t & 63;
  const int wid  = t >> 6;
  const int wm   = wid >> 1;      // batch half (32 rows)
  const int wn   = wid & 1;       // output half (128 cols)
  const int l15  = lane & 15;
  const int lk   = lane >> 4;     // 0..3 k-group

  __shared__ alignas(16) unsigned short xs[64][72];    // +8 pad: 2-way bank (free)
  __shared__ alignas(16) unsigned short ws[256][72];

  const int ty = types[node];
  const float* wb = w + (size_t)ty * (D_OUT * D_IN);
  const float* xb = x + ((size_t)b0 * N_NODE + node) * D_IN;

  f32x4 acc[2][8];
  #pragma unroll
  for (int i = 0; i < 2; ++i)
    #pragma unroll
    for (int j = 0; j < 8; ++j)
      acc[i][j] = (f32x4){0.f, 0.f, 0.f, 0.f};

  // staging decomposition: thread t loads float4 at column group (t&15),
  // rows (t>>4) + p*16.  Destination column permuted: within each 32-wide
  // k-block, source k -> (kgrp(k)=((k>>2)&3))*8 + ((k>>4)&1)*4 + (k&3).
  const int cg  = t & 15;
  const int r0  = t >> 4;
  const int c   = cg * 4;
  const int dst = (c >> 5) * 32 + ((c >> 2) & 3) * 8 + ((c >> 4) & 1) * 4;

  for (int kc = 0; kc < 4; ++kc) {
    const int k0 = kc * 64;
    #pragma unroll
    for (int p = 0; p < 4; ++p) {          // x: 64 rows x 64 cols
      const int row = r0 + p * 16;
      const float4 v = *(const float4*)(xb + (size_t)row * (N_NODE * D_IN) + k0 + c);
      ushort4 bv = { f2bf(v.x), f2bf(v.y), f2bf(v.z), f2bf(v.w) };
      *(ushort4*)&xs[row][dst] = bv;
    }
    #pragma unroll
    for (int p = 0; p < 16; ++p) {         // w: 256 rows x 64 cols
      const int row = r0 + p * 16;
      const float4 v = *(const float4*)(wb + (size_t)row * D_IN + k0 + c);
      ushort4 bv = { f2bf(v.x), f2bf(v.y), f2bf(v.z), f2bf(v.w) };
      *(ushort4*)&ws[row][dst] = bv;
    }
    __syncthreads();
    #pragma unroll
    for (int ks = 0; ks < 2; ++ks) {       // two K=32 steps per chunk
      bf16x8 af[2], bfv[8];
      #pragma unroll
      for (int tm = 0; tm < 2; ++tm)
        af[tm] = *(const bf16x8*)&xs[wm*32 + tm*16 + l15][ks*32 + lk*8];
      #pragma unroll
      for (int tn = 0; tn < 8; ++tn)
        bfv[tn] = *(const bf16x8*)&ws[wn*128 + tn*16 + l15][ks*32 + lk*8];
      #pragma unroll
      for (int tm = 0; tm < 2; ++tm)
        #pragma unroll
        for (int tn = 0; tn < 8; ++tn)
          acc[tm][tn] = __builtin_amdgcn_mfma_f32_16x16x32_bf16(
                            af[tm], bfv[tn], acc[tm][tn], 0, 0, 0);
    }
    __syncthreads();
  }

  // C/D layout (m89-verified): col = lane&15, row = (lane>>4)*4 + reg
  #pragma unroll
  for (int tm = 0; tm < 2; ++tm)
    #pragma unroll
    for (int tn = 0; tn < 8; ++tn)
      #pragma unroll
      for (int r = 0; r < 4; ++r) {
        const int bb = b0 + wm*32 + tm*16 + lk*4 + r;
        const int oo = wn*128 + tn*16 + l15;
        h[((size_t)bb * N_NODE + node) * D_OUT + oo] = acc[tm][tn][r];
      }
}

// Kernel B: out[b][m][o] = sum_n G[m][n] * h[b][n][o] + bias[o], in-place on d_out.
// Thread t owns column o=t of batch b: reads its whole h column into regs first,
// then writes its out column -> no cross-thread/in-place hazard.
__global__ __launch_bounds__(256)
void graph_mix(const float* __restrict__ G, const float* __restrict__ bias,
               float* __restrict__ hb)
{
  const int b = blockIdx.x;
  const int t = threadIdx.x;     // o index, 0..255
  float* base = hb + (size_t)b * (N_NODE * D_OUT);
  float hreg[N_NODE];
  #pragma unroll
  for (int n = 0; n < N_NODE; ++n) hreg[n] = base[(size_t)n * D_OUT + t];
  const float bv = bias[t];
  for (int m = 0; m < N_NODE; ++m) {
    const float* gr = G + m * N_NODE;   // wave-uniform -> scalar loads
    float a0 = 0.f, a1 = 0.f, a2 = 0.f, a3 = 0.f;
    #pragma unroll
    for (int n = 0; n < N_NODE; n += 4) {
      a0 += gr[n]     * hreg[n];
      a1 += gr[n + 1] * hreg[n + 1];
      a2 += gr[n + 2] * hreg[n + 2];
      a3 += gr[n + 3] * hreg[n + 3];
    }
    base[(size_t)m * D_OUT + t] = (a0 + a1) + (a2 + a3) + bv;
  }
}

extern "C" void kernel_launch(void* const* d_in, const int* in_sizes, int n_in,
                              void* d_out, int out_size, void* d_ws, size_t ws_size,
                              hipStream_t stream) {
  const float* x     = (const float*)d_in[0];
  const float* G     = (const float*)d_in[1];
  const float* w     = (const float*)d_in[2];
  const float* bias  = (const float*)d_in[3];
  const int*   types = (const int*)d_in[4];
  float* out = (float*)d_out;

  dim3 gA(B_TOT / 64, N_NODE);
  pernode_gemm<<<gA, 256, 0, stream>>>(x, w, types, out);
  graph_mix<<<B_TOT, 256, 0, stream>>>(G, bias, out);
}

// Round 2
// 102.731 us; speedup vs baseline: 2.4366x; 2.4366x over previous
//
#include <hip/hip_runtime.h>
#include <hip/hip_bf16.h>
#include <cstdint>

#define B_TOT  2048
#define N_NODE 64
#define D_IN   256
#define D_OUT  256
#define N_TYPE 8

typedef __attribute__((ext_vector_type(8))) short bf16x8;
typedef __attribute__((ext_vector_type(4))) float f32x4;
typedef unsigned short u16;

__device__ __forceinline__ u16 f2bf(float f) {
  union { float f; unsigned u; } v; v.f = f;
  unsigned r = v.u + 0x7FFFu + ((v.u >> 16) & 1u);   // round-to-nearest-even
  return (u16)(r >> 16);
}

// k-permutation within a 64-chunk (same on A and B operands -> cancels in MFMA):
//   slot(k) = (k>>5)*32 + ((k>>2)&3)*8 + ((k>>4)&1)*4 + (k&3)
//   16B unit s = slot>>3, elem j = slot&7;  inverse: k = (s>>2)*32 + (j>>2)*16 + (s&3)*4 + (j&3)
// LDS placement of (row r, unit s): u16 index r*64 + (s ^ (r&7))*8   (bank-conflict-free XOR)

// ---- prep: build bf16 images of W and G in ws --------------------------------
__global__ __launch_bounds__(256)
void prep_kernel(const float* __restrict__ w, const float* __restrict__ G,
                 u16* __restrict__ ws)
{
  int e = blockIdx.x * 256 + threadIdx.x;
  if (e < N_TYPE * D_OUT * D_IN) {
    int ty = e >> 16, r = (e >> 8) & 255, k = e & 255;
    int kc = k >> 6, k6 = k & 63;
    int s = (k6 >> 5) * 4 + ((k6 >> 2) & 3);
    int j = ((k6 >> 4) & 1) * 4 + (k6 & 3);
    ws[(size_t)((ty * 4 + kc) * 2048 + r * 8 + (s ^ (r & 7))) * 8 + j] = f2bf(w[e]);
  } else if (e < N_TYPE * D_OUT * D_IN + N_NODE * N_NODE) {
    int g = e - N_TYPE * D_OUT * D_IN;
    int m = g >> 6, n = g & 63;
    int s = (n >> 5) * 4 + ((n >> 2) & 3);
    int j = ((n >> 4) & 1) * 4 + (n & 3);
    ws[524288 + (size_t)(m * 8 + (s ^ (m & 7))) * 8 + j] = f2bf(G[g]);
  }
}

// ---- Kernel A: h[b][n][o] = sum_i W[type[n]][o][i] * x[b][n][i]  -------------
// 256 batches x 256 out per block, one node. 8 waves (4m x 2n). Double-buffered
// LDS, issue-early/write-late pipeline. h stored bf16 into the first 32KB of
// each batch's own 64KB out region (no cross-block aliasing).
__global__ __launch_bounds__(512, 2)
void pernode_gemm(const float* __restrict__ x, const u16* __restrict__ wimg,
                  const int* __restrict__ types, u16* __restrict__ hout)
{
  const int node  = blockIdx.x & 63;
  const int btile = blockIdx.x >> 6;
  const int b0 = btile * 256;
  const int t = threadIdx.x;
  const int lane = t & 63;
  const int wid = t >> 6;
  const int l15 = lane & 15;
  const int lk  = lane >> 4;
  const int wm  = wid & 3;       // rows wm*64
  const int wn  = wid >> 2;      // cols wn*128

  __shared__ u16 lds[4][16384];  // [cur*2 + (0:x,1:w)], 32KB each, 128KB total

  const int ty = types[node];
  const int r  = t >> 1;         // staging row 0..255
  const int hf = t & 1;
  const float* xsrc = x + ((size_t)(b0 + r) * N_NODE + node) * D_IN + hf * 32;
  const u16*   wsrc = wimg + (size_t)ty * 65536 + t * 32;

  f32x4 acc[4][8];
  #pragma unroll
  for (int i = 0; i < 4; ++i)
    #pragma unroll
    for (int j = 0; j < 8; ++j) acc[i][j] = (f32x4){0.f, 0.f, 0.f, 0.f};

  float4 xv[8];
  bf16x8 wv[4];

  // prologue: stage chunk 0 into buf 0
  #pragma unroll
  for (int i = 0; i < 8; ++i) xv[i] = *(const float4*)(xsrc + i * 4);
  #pragma unroll
  for (int i = 0; i < 4; ++i) wv[i] = *(const bf16x8*)(wsrc + i * 8);
  {
    u16* xd = lds[0]; u16* wd = lds[1];
    #pragma unroll
    for (int u = 0; u < 4; ++u) {
      bf16x8 pv;
      #pragma unroll
      for (int j = 0; j < 8; ++j) {
        int fi = ((j >> 2) << 4) + u * 4 + (j & 3);
        pv[j] = (short)f2bf(((const float*)&xv[fi >> 2])[fi & 3]);
      }
      int s = hf * 4 + u;
      *(bf16x8*)&xd[(size_t)r * 64 + (size_t)(s ^ (r & 7)) * 8] = pv;
    }
    #pragma unroll
    for (int i = 0; i < 4; ++i) *(bf16x8*)&wd[(size_t)t * 32 + i * 8] = wv[i];
  }
  __syncthreads();

  for (int kc = 0; kc < 4; ++kc) {
    const int cur = kc & 1;
    if (kc < 3) {   // issue next chunk's loads BEFORE compute (latency hides under MFMA)
      #pragma unroll
      for (int i = 0; i < 8; ++i) xv[i] = *(const float4*)(xsrc + (kc + 1) * 64 + i * 4);
      #pragma unroll
      for (int i = 0; i < 4; ++i) wv[i] = *(const bf16x8*)(wsrc + (kc + 1) * 16384 + i * 8);
    }
    const u16* xb = lds[cur * 2];
    const u16* wb = lds[cur * 2 + 1];
    #pragma unroll
    for (int ks = 0; ks < 2; ++ks) {
      bf16x8 af[4];
      #pragma unroll
      for (int m = 0; m < 4; ++m) {
        int row = wm * 64 + m * 16 + l15;
        af[m] = *(const bf16x8*)&xb[(size_t)row * 64 + (size_t)((ks * 4 + lk) ^ (row & 7)) * 8];
      }
      #pragma unroll
      for (int n = 0; n < 8; ++n) {
        int row = wn * 128 + n * 16 + l15;
        bf16x8 bv = *(const bf16x8*)&wb[(size_t)row * 64 + (size_t)((ks * 4 + lk) ^ (row & 7)) * 8];
        #pragma unroll
        for (int m = 0; m < 4; ++m)
          acc[m][n] = __builtin_amdgcn_mfma_f32_16x16x32_bf16(af[m], bv, acc[m][n], 0, 0, 0);
      }
    }
    if (kc < 3) {   // write-late into the other buffer
      u16* xd = lds[(cur ^ 1) * 2]; u16* wd = lds[(cur ^ 1) * 2 + 1];
      #pragma unroll
      for (int u = 0; u < 4; ++u) {
        bf16x8 pv;
        #pragma unroll
        for (int j = 0; j < 8; ++j) {
          int fi = ((j >> 2) << 4) + u * 4 + (j & 3);
          pv[j] = (short)f2bf(((const float*)&xv[fi >> 2])[fi & 3]);
        }
        int s = hf * 4 + u;
        *(bf16x8*)&xd[(size_t)r * 64 + (size_t)(s ^ (r & 7)) * 8] = pv;
      }
      #pragma unroll
      for (int i = 0; i < 4; ++i) *(bf16x8*)&wd[(size_t)t * 32 + i * 8] = wv[i];
    }
    __syncthreads();
  }

  // epilogue: acc -> LDS (bf16, unit-swizzled) -> coalesced 16B global stores
  u16* hl = &lds[0][0];   // 256 rows x 256 cols u16 = 128KB
  #pragma unroll
  for (int m = 0; m < 4; ++m)
    #pragma unroll
    for (int n = 0; n < 8; ++n)
      #pragma unroll
      for (int rr = 0; rr < 4; ++rr) {
        int rowl = wm * 64 + m * 16 + lk * 4 + rr;   // C/D: row = (lane>>4)*4+reg
        int col  = wn * 128 + n * 16 + l15;          //      col = lane&15
        hl[(size_t)rowl * 256 + (size_t)((col >> 3) ^ (rowl & 31)) * 8 + (col & 7)] =
            f2bf(acc[m][n][rr]);
      }
  __syncthreads();
  u16* dst = hout + (size_t)(b0 + r) * 32768 + node * 256 + hf * 128;
  #pragma unroll
  for (int i = 0; i < 16; ++i) {
    int u = hf * 16 + i;
    bf16x8 v = *(const bf16x8*)&hl[(size_t)r * 256 + (size_t)(u ^ (r & 31)) * 8];
    *(bf16x8*)(dst + i * 8) = v;
  }
}

// ---- Kernel B: out[b][m][o] = sum_n G[m][n]*h[b][n][o] + bias[o], MFMA, in-place
__global__ __launch_bounds__(256)
void graph_mix(const u16* __restrict__ gimg, const float* __restrict__ bias,
               float* __restrict__ out)
{
  const int b = blockIdx.x;
  const int t = threadIdx.x;
  const int lane = t & 63, wid = t >> 6, l15 = lane & 15, lk = lane >> 4;

  __shared__ u16 himg[16384];   // [n][o] bf16, linear
  __shared__ u16 gl[4096];      // G image (perm+swizzle baked by prep)

  const u16* hsrc = (const u16*)((const char*)out + (size_t)b * 65536);
  bf16x8 hv[8], gv[2];
  #pragma unroll
  for (int i = 0; i < 8; ++i) hv[i] = *(const bf16x8*)(hsrc + t * 64 + i * 8);
  #pragma unroll
  for (int i = 0; i < 2; ++i) gv[i] = *(const bf16x8*)(gimg + t * 16 + i * 8);
  float bb[4];
  #pragma unroll
  for (int nt = 0; nt < 4; ++nt) bb[nt] = bias[wid * 64 + nt * 16 + l15];
  #pragma unroll
  for (int i = 0; i < 8; ++i) *(bf16x8*)&himg[t * 64 + i * 8] = hv[i];
  #pragma unroll
  for (int i = 0; i < 2; ++i) *(bf16x8*)&gl[t * 16 + i * 8] = gv[i];
  __syncthreads();   // drains vmcnt: all global h reads complete before any out write

  f32x4 acc[4][4];
  #pragma unroll
  for (int i = 0; i < 4; ++i)
    #pragma unroll
    for (int j = 0; j < 4; ++j) acc[i][j] = (f32x4){0.f, 0.f, 0.f, 0.f};

  #pragma unroll
  for (int ks = 0; ks < 2; ++ks) {
    bf16x8 ag[4];
    #pragma unroll
    for (int mt = 0; mt < 4; ++mt) {
      int row = mt * 16 + l15;
      ag[mt] = *(const bf16x8*)&gl[(size_t)row * 64 + (size_t)((ks * 4 + lk) ^ (row & 7)) * 8];
    }
    #pragma unroll
    for (int nt = 0; nt < 4; ++nt) {
      int o = wid * 64 + nt * 16 + l15;
      bf16x8 bh;
      #pragma unroll
      for (int j = 0; j < 8; ++j) {   // gather h with the same k-perm as G's image
        int nk = ks * 32 + lk * 4 + (j & 3) + ((j >> 2) << 4);
        bh[j] = (short)himg[nk * 256 + o];
      }
      #pragma unroll
      for (int mt = 0; mt < 4; ++mt)
        acc[mt][nt] = __builtin_amdgcn_mfma_f32_16x16x32_bf16(ag[mt], bh, acc[mt][nt], 0, 0, 0);
    }
  }
  float* ob = out + (size_t)b * 16384;
  #pragma unroll
  for (int mt = 0; mt < 4; ++mt)
    #pragma unroll
    for (int nt = 0; nt < 4; ++nt)
      #pragma unroll
      for (int rr = 0; rr < 4; ++rr) {
        int m = mt * 16 + lk * 4 + rr;
        int o = wid * 64 + nt * 16 + l15;
        ob[(size_t)m * 256 + o] = acc[mt][nt][rr] + bb[nt];
      }
}

// ---- fallback (round-1, passing) — used only if ws_size is too small --------
__global__ __launch_bounds__(256)
void pernode_gemm_fb(const float* __restrict__ x, const float* __restrict__ w,
                     const int* __restrict__ types, float* __restrict__ h)
{
  const int node = blockIdx.y;
  const int b0   = blockIdx.x * 64;
  const int t    = threadIdx.x;
  const int lane = t & 63;
  const int wid  = t >> 6;
  const int wm   = wid >> 1;
  const int wn   = wid & 1;
  const int l15  = lane & 15;
  const int lk   = lane >> 4;

  __shared__ alignas(16) u16 xs[64][72];
  __shared__ alignas(16) u16 wsm[256][72];

  const int ty = types[node];
  const float* wb = w + (size_t)ty * (D_OUT * D_IN);
  const float* xb = x + ((size_t)b0 * N_NODE + node) * D_IN;

  f32x4 acc[2][8];
  #pragma unroll
  for (int i = 0; i < 2; ++i)
    #pragma unroll
    for (int j = 0; j < 8; ++j) acc[i][j] = (f32x4){0.f,0.f,0.f,0.f};

  const int cg = t & 15, r0 = t >> 4, c = cg * 4;
  const int dst = (c >> 5) * 32 + ((c >> 2) & 3) * 8 + ((c >> 4) & 1) * 4;

  for (int kc = 0; kc < 4; ++kc) {
    const int k0 = kc * 64;
    #pragma unroll
    for (int p = 0; p < 4; ++p) {
      const int row = r0 + p * 16;
      const float4 v = *(const float4*)(xb + (size_t)row * (N_NODE * D_IN) + k0 + c);
      ushort4 bv = { f2bf(v.x), f2bf(v.y), f2bf(v.z), f2bf(v.w) };
      *(ushort4*)&xs[row][dst] = bv;
    }
    #pragma unroll
    for (int p = 0; p < 16; ++p) {
      const int row = r0 + p * 16;
      const float4 v = *(const float4*)(wb + (size_t)row * D_IN + k0 + c);
      ushort4 bv = { f2bf(v.x), f2bf(v.y), f2bf(v.z), f2bf(v.w) };
      *(ushort4*)&wsm[row][dst] = bv;
    }
    __syncthreads();
    #pragma unroll
    for (int ks = 0; ks < 2; ++ks) {
      bf16x8 af[2], bfv[8];
      #pragma unroll
      for (int tm = 0; tm < 2; ++tm)
        af[tm] = *(const bf16x8*)&xs[wm*32 + tm*16 + l15][ks*32 + lk*8];
      #pragma unroll
      for (int tn = 0; tn < 8; ++tn)
        bfv[tn] = *(const bf16x8*)&wsm[wn*128 + tn*16 + l15][ks*32 + lk*8];
      #pragma unroll
      for (int tm = 0; tm < 2; ++tm)
        #pragma unroll
        for (int tn = 0; tn < 8; ++tn)
          acc[tm][tn] = __builtin_amdgcn_mfma_f32_16x16x32_bf16(af[tm], bfv[tn], acc[tm][tn], 0, 0, 0);
    }
    __syncthreads();
  }
  #pragma unroll
  for (int tm = 0; tm < 2; ++tm)
    #pragma unroll
    for (int tn = 0; tn < 8; ++tn)
      #pragma unroll
      for (int rr = 0; rr < 4; ++rr) {
        const int bb2 = b0 + wm*32 + tm*16 + lk*4 + rr;
        const int oo  = wn*128 + tn*16 + l15;
        h[((size_t)bb2 * N_NODE + node) * D_OUT + oo] = acc[tm][tn][rr];
      }
}

__global__ __launch_bounds__(256)
void graph_mix_fb(const float* __restrict__ G, const float* __restrict__ bias,
                  float* __restrict__ hb)
{
  const int b = blockIdx.x;
  const int t = threadIdx.x;
  float* base = hb + (size_t)b * (N_NODE * D_OUT);
  float hreg[N_NODE];
  #pragma unroll
  for (int n = 0; n < N_NODE; ++n) hreg[n] = base[(size_t)n * D_OUT + t];
  const float bv = bias[t];
  for (int m = 0; m < N_NODE; ++m) {
    const float* gr = G + m * N_NODE;
    float a0 = 0.f, a1 = 0.f, a2 = 0.f, a3 = 0.f;
    #pragma unroll
    for (int n = 0; n < N_NODE; n += 4) {
      a0 += gr[n]     * hreg[n];
      a1 += gr[n + 1] * hreg[n + 1];
      a2 += gr[n + 2] * hreg[n + 2];
      a3 += gr[n + 3] * hreg[n + 3];
    }
    base[(size_t)m * D_OUT + t] = (a0 + a1) + (a2 + a3) + bv;
  }
}

extern "C" void kernel_launch(void* const* d_in, const int* in_sizes, int n_in,
                              void* d_out, int out_size, void* d_ws, size_t ws_size,
                              hipStream_t stream) {
  const float* x     = (const float*)d_in[0];
  const float* G     = (const float*)d_in[1];
  const float* w     = (const float*)d_in[2];
  const float* bias  = (const float*)d_in[3];
  const int*   types = (const int*)d_in[4];

  const size_t WS_NEED = (size_t)(524288 + 4096) * 2;   // W img 1MB + G img 8KB
  if (ws_size >= WS_NEED) {
    u16* ws = (u16*)d_ws;
    prep_kernel<<<2064, 256, 0, stream>>>(w, G, ws);
    pernode_gemm<<<512, 512, 0, stream>>>(x, ws, types, (u16*)d_out);
    graph_mix<<<2048, 256, 0, stream>>>(ws + 524288, bias, (float*)d_out);
  } else {
    dim3 gA(B_TOT / 64, N_NODE);
    pernode_gemm_fb<<<gA, 256, 0, stream>>>(x, w, types, (float*)d_out);
    graph_mix_fb<<<B_TOT, 256, 0, stream>>>(G, bias, (float*)d_out);
  }
}